// Round 6
// baseline (862.071 us; speedup 1.0000x reference)
//
#include <hip/hip_runtime.h>
#include <hip/hip_bf16.h>

// StructuralEncoder: gather(3x128 f32) -> 384->256->256->128 MLP (relu,relu,linear)
// -> mean over 1M rows -> 128->256->128 head.
// R6: revert to 16x16x32 MFMA (R4 structure = 508us). LDS cut 48->32KB by
// splitting L1 K-loop: stage c0+c1, compute kk0-7 while c2 loads fly, overwrite
// chunk0 with c2, finish kk8-11. h1/h2 overlay same 32KB. 7 barriers,
// 4-5 blocks/CU. Fused single prep kernel.

#define EMBED 128
#define BM 64
#define NBUCKET 128

typedef __bf16 bf16x8 __attribute__((ext_vector_type(8)));
typedef __bf16 bf16x4 __attribute__((ext_vector_type(4)));
typedef float f32x4 __attribute__((ext_vector_type(4)));

// pack W (K x N row-major) into 16(feature)x32(k) A-frag tiles for 16x16x32,
// and zero partial buckets. dst[((mt*(K/32)+kt)*64+l)*8+j] =
// src[(kt*32+(l>>4)*8+j)*N + mt*16+(l&15)]
__global__ void prep_all(const float* __restrict__ W1, const float* __restrict__ W2,
                         const float* __restrict__ W3,
                         __bf16* __restrict__ W1p, __bf16* __restrict__ W2p,
                         __bf16* __restrict__ W3p, float* __restrict__ prt) {
    int idx = blockIdx.x * 256 + threadIdx.x;
    if (idx < NBUCKET * 128) prt[idx] = 0.f;
    const float* src; __bf16* dst; int K, N, e;
    if (idx < 98304)       { src = W1; dst = W1p; K = 384; N = 256; e = idx; }
    else if (idx < 163840) { src = W2; dst = W2p; K = 256; N = 256; e = idx - 98304; }
    else if (idx < 196608) { src = W3; dst = W3p; K = 256; N = 128; e = idx - 163840; }
    else return;
    int j = e & 7, l = (e >> 3) & 63, t = e >> 9;
    int KT = K >> 5;
    int kt = t % KT, mt = t / KT;
    int k  = kt * 32 + (l >> 4) * 8 + j;
    int nc = mt * 16 + (l & 15);
    dst[e] = (__bf16)src[k * N + nc];
}

// ---- main fused MLP over 64-row tiles ----
__global__ __launch_bounds__(256, 4) void mlp_main(
    const int* __restrict__ triples,
    const float* __restrict__ ent, const float* __restrict__ rel,
    const __bf16* __restrict__ W1p, const float* __restrict__ b1,
    const __bf16* __restrict__ W2p, const float* __restrict__ b2,
    const __bf16* __restrict__ W3p,
    float* __restrict__ part, int n)
{
    // LDS 32KB, time-multiplexed:
    //   xbuf0 [0,16K), xbuf1 [16K,32K): 64 rows x 256B (128 bf16) per c-chunk
    //   c0->xbuf0, c1->xbuf1; after kk0-7 reads, c2->xbuf0
    //   h1s/h2s overlay [0,32K) = 64 x 512B after all x reads done
    __shared__ unsigned char lds[32768];
    unsigned char* h1s = lds;
    unsigned char* h2s = lds;

    const int tid  = threadIdx.x;
    const int wave = tid >> 6;
    const int lane = tid & 63;
    const int l15  = lane & 15;
    const int l4   = lane >> 4;
    const int s0   = blockIdx.x * BM;
    const int sp   = tid >> 4;   // sample subgroup for staging
    const int ch   = tid & 15;   // 16B bf16 chunk (8 floats) within a c-row

    // ---- prologue: triple indices; issue c0+c1 gathers ----
    int rows[3][4];
#pragma unroll
    for (int p = 0; p < 4; p++) {
        int g = s0 + p * 16 + sp;
        const int* t = triples + (g < n ? g : 0) * 3;
        rows[0][p] = t[0]; rows[1][p] = t[1]; rows[2][p] = t[2];
    }
    float4 ga[2][4], gb[2][4];
#pragma unroll
    for (int c = 0; c < 2; c++) {
        const float* tbl = (c == 1) ? rel : ent;
#pragma unroll
        for (int p = 0; p < 4; p++) {
            const float* src = tbl + (long)rows[c][p] * EMBED + ch * 8;
            ga[c][p] = *(const float4*)src;
            gb[c][p] = *(const float4*)(src + 4);
        }
    }
    // cvt + write c0 -> xbuf0, c1 -> xbuf1 (256B row stride, 16B-chunk swizzle)
#pragma unroll
    for (int c = 0; c < 2; c++)
#pragma unroll
        for (int p = 0; p < 4; p++) {
            bf16x8 w;
            w[0] = (__bf16)ga[c][p].x; w[1] = (__bf16)ga[c][p].y;
            w[2] = (__bf16)ga[c][p].z; w[3] = (__bf16)ga[c][p].w;
            w[4] = (__bf16)gb[c][p].x; w[5] = (__bf16)gb[c][p].y;
            w[6] = (__bf16)gb[c][p].z; w[7] = (__bf16)gb[c][p].w;
            int s = p * 16 + sp;
            int off = c * 16384 + ((s * 256 + ch * 16) ^ ((s & 7) << 4));
            *(bf16x8*)(lds + off) = w;
        }
    __syncthreads();  // B1: c0,c1 ready

    // issue c2 gathers; latency hides under kk0-7 compute
    float4 g2a[4], g2b[4];
#pragma unroll
    for (int p = 0; p < 4; p++) {
        const float* src = ent + (long)rows[2][p] * EMBED + ch * 8;
        g2a[p] = *(const float4*)src;
        g2b[p] = *(const float4*)(src + 4);
    }

    // ========== Layer 1: h1 = relu(x @ W1 + b1), K=384, 12 k-steps ==========
    f32x4 acc[4][4];
    {
        const int fb = wave * 64;
#pragma unroll
        for (int m = 0; m < 4; m++) {
            f32x4 bias = *(const f32x4*)(b1 + fb + m * 16 + l4 * 4);
#pragma unroll
            for (int nn = 0; nn < 4; nn++) acc[m][nn] = bias;
        }
    }
    __builtin_amdgcn_s_setprio(1);
#pragma unroll
    for (int kk = 0; kk < 8; kk++) {
        bf16x8 bfr[4];
#pragma unroll
        for (int nn = 0; nn < 4; nn++) {
            int s = nn * 16 + l15;
            int off = (kk >> 2) * 16384 +
                      ((s * 256 + (kk & 3) * 64 + l4 * 16) ^ ((s & 7) << 4));
            bfr[nn] = *(const bf16x8*)(lds + off);
        }
        bf16x8 afr[4];
#pragma unroll
        for (int m = 0; m < 4; m++)
            afr[m] = *(const bf16x8*)(W1p + ((wave * 4 + m) * 12 + kk) * 512 + lane * 8);
#pragma unroll
        for (int m = 0; m < 4; m++)
#pragma unroll
            for (int nn = 0; nn < 4; nn++)
                acc[m][nn] = __builtin_amdgcn_mfma_f32_16x16x32_bf16(
                    afr[m], bfr[nn], acc[m][nn], 0, 0, 0);
    }
    __builtin_amdgcn_s_setprio(0);
    __syncthreads();  // B2: kk0-7 reads done; xbuf0 may be overwritten
    // write c2 -> xbuf0
#pragma unroll
    for (int p = 0; p < 4; p++) {
        bf16x8 w;
        w[0] = (__bf16)g2a[p].x; w[1] = (__bf16)g2a[p].y;
        w[2] = (__bf16)g2a[p].z; w[3] = (__bf16)g2a[p].w;
        w[4] = (__bf16)g2b[p].x; w[5] = (__bf16)g2b[p].y;
        w[6] = (__bf16)g2b[p].z; w[7] = (__bf16)g2b[p].w;
        int s = p * 16 + sp;
        int off = (s * 256 + ch * 16) ^ ((s & 7) << 4);
        *(bf16x8*)(lds + off) = w;
    }
    __syncthreads();  // B3: c2 ready
    __builtin_amdgcn_s_setprio(1);
#pragma unroll
    for (int kk = 8; kk < 12; kk++) {
        bf16x8 bfr[4];
#pragma unroll
        for (int nn = 0; nn < 4; nn++) {
            int s = nn * 16 + l15;
            int off = (s * 256 + (kk & 3) * 64 + l4 * 16) ^ ((s & 7) << 4);
            bfr[nn] = *(const bf16x8*)(lds + off);
        }
        bf16x8 afr[4];
#pragma unroll
        for (int m = 0; m < 4; m++)
            afr[m] = *(const bf16x8*)(W1p + ((wave * 4 + m) * 12 + kk) * 512 + lane * 8);
#pragma unroll
        for (int m = 0; m < 4; m++)
#pragma unroll
            for (int nn = 0; nn < 4; nn++)
                acc[m][nn] = __builtin_amdgcn_mfma_f32_16x16x32_bf16(
                    afr[m], bfr[nn], acc[m][nn], 0, 0, 0);
    }
    __builtin_amdgcn_s_setprio(0);
    __syncthreads();  // B4: all x reads done; h1 may overlay [0,32K)
    // write h1 (relu, bf16)
#pragma unroll
    for (int m = 0; m < 4; m++) {
        int f0 = wave * 64 + m * 16 + l4 * 4;
#pragma unroll
        for (int nn = 0; nn < 4; nn++) {
            int s = nn * 16 + l15;
            bf16x4 p;
#pragma unroll
            for (int j = 0; j < 4; j++) {
                float v = acc[m][nn][j];
                p[j] = (__bf16)(v > 0.f ? v : 0.f);
            }
            int off = (s * 512 + f0 * 2) ^ ((s & 7) << 4);
            *(bf16x4*)(h1s + off) = p;
        }
    }
    __syncthreads();  // B5: h1 ready

    // ========== Layer 2: h2 = relu(h1 @ W2 + b2), K=256 ==========
    f32x4 acc2[4][4];
    {
        const int fb = wave * 64;
#pragma unroll
        for (int m = 0; m < 4; m++) {
            f32x4 bias = *(const f32x4*)(b2 + fb + m * 16 + l4 * 4);
#pragma unroll
            for (int nn = 0; nn < 4; nn++) acc2[m][nn] = bias;
        }
    }
    __builtin_amdgcn_s_setprio(1);
#pragma unroll
    for (int kk = 0; kk < 8; kk++) {
        bf16x8 bfr[4];
#pragma unroll
        for (int nn = 0; nn < 4; nn++) {
            int s = nn * 16 + l15;
            int off = (s * 512 + kk * 64 + l4 * 16) ^ ((s & 7) << 4);
            bfr[nn] = *(const bf16x8*)(h1s + off);
        }
        bf16x8 afr[4];
#pragma unroll
        for (int m = 0; m < 4; m++)
            afr[m] = *(const bf16x8*)(W2p + ((wave * 4 + m) * 8 + kk) * 512 + lane * 8);
#pragma unroll
        for (int m = 0; m < 4; m++)
#pragma unroll
            for (int nn = 0; nn < 4; nn++)
                acc2[m][nn] = __builtin_amdgcn_mfma_f32_16x16x32_bf16(
                    afr[m], bfr[nn], acc2[m][nn], 0, 0, 0);
    }
    __builtin_amdgcn_s_setprio(0);
    __syncthreads();  // B6: all h1 reads done; h2 may overwrite region
    // write h2 (relu, bf16)
#pragma unroll
    for (int m = 0; m < 4; m++) {
        int f0 = wave * 64 + m * 16 + l4 * 4;
#pragma unroll
        for (int nn = 0; nn < 4; nn++) {
            int s = nn * 16 + l15;
            bf16x4 p;
#pragma unroll
            for (int j = 0; j < 4; j++) {
                float v = acc2[m][nn][j];
                p[j] = (__bf16)(v > 0.f ? v : 0.f);
            }
            int off = (s * 512 + f0 * 2) ^ ((s & 7) << 4);
            *(bf16x4*)(h2s + off) = p;
        }
    }
    __syncthreads();  // B7: h2 ready

    // ========== Layer 3: enc = h2 @ W3 (bias in head), K=256 ==========
    f32x4 acc3[2][4];
#pragma unroll
    for (int m = 0; m < 2; m++)
#pragma unroll
        for (int nn = 0; nn < 4; nn++)
            acc3[m][nn] = (f32x4)(0.f);
    __builtin_amdgcn_s_setprio(1);
#pragma unroll
    for (int kk = 0; kk < 8; kk++) {
        bf16x8 bfr[4];
#pragma unroll
        for (int nn = 0; nn < 4; nn++) {
            int s = nn * 16 + l15;
            int off = (s * 512 + kk * 64 + l4 * 16) ^ ((s & 7) << 4);
            bfr[nn] = *(const bf16x8*)(h2s + off);
        }
        bf16x8 afr[2];
#pragma unroll
        for (int m = 0; m < 2; m++)
            afr[m] = *(const bf16x8*)(W3p + ((wave * 2 + m) * 8 + kk) * 512 + lane * 8);
#pragma unroll
        for (int m = 0; m < 2; m++)
#pragma unroll
            for (int nn = 0; nn < 4; nn++)
                acc3[m][nn] = __builtin_amdgcn_mfma_f32_16x16x32_bf16(
                    afr[m], bfr[nn], acc3[m][nn], 0, 0, 0);
    }
    __builtin_amdgcn_s_setprio(0);
    // reduce over samples, accumulate into bucket
    {
        float* bucket = part + (blockIdx.x & (NBUCKET - 1)) * 128;
#pragma unroll
        for (int m = 0; m < 2; m++) {
#pragma unroll
            for (int j = 0; j < 4; j++) {
                float v = 0.f;
#pragma unroll
                for (int nn = 0; nn < 4; nn++) {
                    int g = s0 + nn * 16 + l15;
                    float t = acc3[m][nn][j];
                    v += (g < n) ? t : 0.f;
                }
                for (int off = 1; off < 16; off <<= 1) v += __shfl_xor(v, off);
                if (l15 == 0) {
                    int f = wave * 32 + m * 16 + l4 * 4 + j;
                    atomicAdd(bucket + f, v);
                }
            }
        }
    }
}

// ---- head: agg = sum/n + b3; out = relu(agg@Wf1+bf1)@Wf2+bf2 (f32) ----
__global__ void head_kernel(const float* __restrict__ part, const float* __restrict__ b3,
                            const float* __restrict__ Wf1, const float* __restrict__ bf1,
                            const float* __restrict__ Wf2, const float* __restrict__ bf2,
                            float* __restrict__ out, int n)
{
    __shared__ float agg[128];
    __shared__ float t[256];
    const int tid = threadIdx.x;
    if (tid < 128) {
        float s = 0.f;
        for (int b = 0; b < NBUCKET; b++) s += part[b * 128 + tid];
        agg[tid] = s / (float)n + b3[tid];
    }
    __syncthreads();
    {
        float a = bf1[tid];
        for (int k = 0; k < 128; k++) a += agg[k] * Wf1[k * 256 + tid];
        t[tid] = a > 0.f ? a : 0.f;
    }
    __syncthreads();
    if (tid < 128) {
        float o = bf2[tid];
        for (int i = 0; i < 256; i++) o += t[i] * Wf2[i * 128 + tid];
        out[tid] = o;
    }
}

extern "C" void kernel_launch(void* const* d_in, const int* in_sizes, int n_in,
                              void* d_out, int out_size, void* d_ws, size_t ws_size,
                              hipStream_t stream) {
    const int*   triples = (const int*)d_in[0];
    const float* ent     = (const float*)d_in[1];
    const float* rel     = (const float*)d_in[2];
    const float* W1      = (const float*)d_in[3];
    const float* b1      = (const float*)d_in[4];
    const float* W2      = (const float*)d_in[5];
    const float* b2      = (const float*)d_in[6];
    const float* W3      = (const float*)d_in[7];
    const float* b3      = (const float*)d_in[8];
    const float* Wf1     = (const float*)d_in[9];
    const float* bf1     = (const float*)d_in[10];
    const float* Wf2     = (const float*)d_in[11];
    const float* bf2     = (const float*)d_in[12];
    float* out = (float*)d_out;
    const int n = in_sizes[0] / 3;

    // ws layout (bytes): W1p[0,196608) W2p[196608,327680) W3p[327680,393216)
    //                    part[393216,458752)
    __bf16* W1p = (__bf16*)d_ws;
    __bf16* W2p = (__bf16*)((char*)d_ws + 196608);
    __bf16* W3p = (__bf16*)((char*)d_ws + 327680);
    float*  prt = (float*)((char*)d_ws + 393216);

    prep_all<<<768, 256, 0, stream>>>(W1, W2, W3, W1p, W2p, W3p, prt);

    const int blocks = (n + BM - 1) / BM;
    mlp_main<<<blocks, 256, 0, stream>>>(triples, ent, rel, W1p, b1, W2p, b2, W3p, prt, n);
    head_kernel<<<1, 256, 0, stream>>>(prt, b3, Wf1, bf1, Wf2, bf2, out, n);
}

// Round 7
// 802.299 us; speedup vs baseline: 1.0745x; 1.0745x over previous
//
#include <hip/hip_runtime.h>
#include <hip/hip_bf16.h>

// StructuralEncoder: gather(3x128 f32) -> 384->256->256->128 MLP (relu,relu,linear)
// -> mean over 1M rows -> 128->256->128 head.
// R7: R6 structure (32KB LDS, split L1 K-loop, 7 barriers, 4 blocks/CU) but c2
// gather loads issued AFTER kk0-7 MFMA loop, right before B2 -> short live
// range, no spill under the 128-VGPR cap (R6 spilled: WRITE_SIZE 31K->1.5M KB).

#define EMBED 128
#define BM 64
#define NBUCKET 128

typedef __bf16 bf16x8 __attribute__((ext_vector_type(8)));
typedef __bf16 bf16x4 __attribute__((ext_vector_type(4)));
typedef float f32x4 __attribute__((ext_vector_type(4)));

// pack W (K x N row-major) into 16(feature)x32(k) A-frag tiles for 16x16x32,
// and zero partial buckets.
__global__ void prep_all(const float* __restrict__ W1, const float* __restrict__ W2,
                         const float* __restrict__ W3,
                         __bf16* __restrict__ W1p, __bf16* __restrict__ W2p,
                         __bf16* __restrict__ W3p, float* __restrict__ prt) {
    int idx = blockIdx.x * 256 + threadIdx.x;
    if (idx < NBUCKET * 128) prt[idx] = 0.f;
    const float* src; __bf16* dst; int K, N, e;
    if (idx < 98304)       { src = W1; dst = W1p; K = 384; N = 256; e = idx; }
    else if (idx < 163840) { src = W2; dst = W2p; K = 256; N = 256; e = idx - 98304; }
    else if (idx < 196608) { src = W3; dst = W3p; K = 256; N = 128; e = idx - 163840; }
    else return;
    int j = e & 7, l = (e >> 3) & 63, t = e >> 9;
    int KT = K >> 5;
    int kt = t % KT, mt = t / KT;
    int k  = kt * 32 + (l >> 4) * 8 + j;
    int nc = mt * 16 + (l & 15);
    dst[e] = (__bf16)src[k * N + nc];
}

// ---- main fused MLP over 64-row tiles ----
__global__ __launch_bounds__(256, 4) void mlp_main(
    const int* __restrict__ triples,
    const float* __restrict__ ent, const float* __restrict__ rel,
    const __bf16* __restrict__ W1p, const float* __restrict__ b1,
    const __bf16* __restrict__ W2p, const float* __restrict__ b2,
    const __bf16* __restrict__ W3p,
    float* __restrict__ part, int n)
{
    // LDS 32KB, time-multiplexed:
    //   xbuf0 [0,16K), xbuf1 [16K,32K): 64 rows x 256B (128 bf16) per c-chunk
    //   c0->xbuf0, c1->xbuf1; after kk0-7 reads, c2->xbuf0
    //   h1s/h2s overlay [0,32K) = 64 x 512B after all x reads done
    __shared__ unsigned char lds[32768];
    unsigned char* h1s = lds;
    unsigned char* h2s = lds;

    const int tid  = threadIdx.x;
    const int wave = tid >> 6;
    const int lane = tid & 63;
    const int l15  = lane & 15;
    const int l4   = lane >> 4;
    const int s0   = blockIdx.x * BM;
    const int sp   = tid >> 4;   // sample subgroup for staging
    const int ch   = tid & 15;   // 16B bf16 chunk (8 floats) within a c-row

    // ---- prologue: triple indices; issue c0+c1 gathers ----
    int rows[3][4];
#pragma unroll
    for (int p = 0; p < 4; p++) {
        int g = s0 + p * 16 + sp;
        const int* t = triples + (g < n ? g : 0) * 3;
        rows[0][p] = t[0]; rows[1][p] = t[1]; rows[2][p] = t[2];
    }
    {
        float4 ga[2][4], gb[2][4];
#pragma unroll
        for (int c = 0; c < 2; c++) {
            const float* tbl = (c == 1) ? rel : ent;
#pragma unroll
            for (int p = 0; p < 4; p++) {
                const float* src = tbl + (long)rows[c][p] * EMBED + ch * 8;
                ga[c][p] = *(const float4*)src;
                gb[c][p] = *(const float4*)(src + 4);
            }
        }
        // cvt + write c0 -> xbuf0, c1 -> xbuf1 (256B row stride, swizzled)
#pragma unroll
        for (int c = 0; c < 2; c++)
#pragma unroll
            for (int p = 0; p < 4; p++) {
                bf16x8 w;
                w[0] = (__bf16)ga[c][p].x; w[1] = (__bf16)ga[c][p].y;
                w[2] = (__bf16)ga[c][p].z; w[3] = (__bf16)ga[c][p].w;
                w[4] = (__bf16)gb[c][p].x; w[5] = (__bf16)gb[c][p].y;
                w[6] = (__bf16)gb[c][p].z; w[7] = (__bf16)gb[c][p].w;
                int s = p * 16 + sp;
                int off = c * 16384 + ((s * 256 + ch * 16) ^ ((s & 7) << 4));
                *(bf16x8*)(lds + off) = w;
            }
    }
    __syncthreads();  // B1: c0,c1 ready

    // ========== Layer 1: h1 = relu(x @ W1 + b1), K=384, 12 k-steps ==========
    f32x4 acc[4][4];
    {
        const int fb = wave * 64;
#pragma unroll
        for (int m = 0; m < 4; m++) {
            f32x4 bias = *(const f32x4*)(b1 + fb + m * 16 + l4 * 4);
#pragma unroll
            for (int nn = 0; nn < 4; nn++) acc[m][nn] = bias;
        }
    }
    __builtin_amdgcn_s_setprio(1);
#pragma unroll
    for (int kk = 0; kk < 8; kk++) {
        bf16x8 bfr[4];
#pragma unroll
        for (int nn = 0; nn < 4; nn++) {
            int s = nn * 16 + l15;
            int off = (kk >> 2) * 16384 +
                      ((s * 256 + (kk & 3) * 64 + l4 * 16) ^ ((s & 7) << 4));
            bfr[nn] = *(const bf16x8*)(lds + off);
        }
        bf16x8 afr[4];
#pragma unroll
        for (int m = 0; m < 4; m++)
            afr[m] = *(const bf16x8*)(W1p + ((wave * 4 + m) * 12 + kk) * 512 + lane * 8);
#pragma unroll
        for (int m = 0; m < 4; m++)
#pragma unroll
            for (int nn = 0; nn < 4; nn++)
                acc[m][nn] = __builtin_amdgcn_mfma_f32_16x16x32_bf16(
                    afr[m], bfr[nn], acc[m][nn], 0, 0, 0);
    }
    __builtin_amdgcn_s_setprio(0);
    // issue c2 gathers NOW (short live range: only across B2); latency overlaps
    // the barrier drain + co-resident blocks' compute
    float4 g2a[4], g2b[4];
#pragma unroll
    for (int p = 0; p < 4; p++) {
        const float* src = ent + (long)rows[2][p] * EMBED + ch * 8;
        g2a[p] = *(const float4*)src;
        g2b[p] = *(const float4*)(src + 4);
    }
    __syncthreads();  // B2: kk0-7 reads done; xbuf0 may be overwritten
    // write c2 -> xbuf0
#pragma unroll
    for (int p = 0; p < 4; p++) {
        bf16x8 w;
        w[0] = (__bf16)g2a[p].x; w[1] = (__bf16)g2a[p].y;
        w[2] = (__bf16)g2a[p].z; w[3] = (__bf16)g2a[p].w;
        w[4] = (__bf16)g2b[p].x; w[5] = (__bf16)g2b[p].y;
        w[6] = (__bf16)g2b[p].z; w[7] = (__bf16)g2b[p].w;
        int s = p * 16 + sp;
        int off = (s * 256 + ch * 16) ^ ((s & 7) << 4);
        *(bf16x8*)(lds + off) = w;
    }
    __syncthreads();  // B3: c2 ready
    __builtin_amdgcn_s_setprio(1);
#pragma unroll
    for (int kk = 8; kk < 12; kk++) {
        bf16x8 bfr[4];
#pragma unroll
        for (int nn = 0; nn < 4; nn++) {
            int s = nn * 16 + l15;
            int off = (s * 256 + (kk & 3) * 64 + l4 * 16) ^ ((s & 7) << 4);
            bfr[nn] = *(const bf16x8*)(lds + off);
        }
        bf16x8 afr[4];
#pragma unroll
        for (int m = 0; m < 4; m++)
            afr[m] = *(const bf16x8*)(W1p + ((wave * 4 + m) * 12 + kk) * 512 + lane * 8);
#pragma unroll
        for (int m = 0; m < 4; m++)
#pragma unroll
            for (int nn = 0; nn < 4; nn++)
                acc[m][nn] = __builtin_amdgcn_mfma_f32_16x16x32_bf16(
                    afr[m], bfr[nn], acc[m][nn], 0, 0, 0);
    }
    __builtin_amdgcn_s_setprio(0);
    __syncthreads();  // B4: all x reads done; h1 may overlay [0,32K)
    // write h1 (relu, bf16)
#pragma unroll
    for (int m = 0; m < 4; m++) {
        int f0 = wave * 64 + m * 16 + l4 * 4;
#pragma unroll
        for (int nn = 0; nn < 4; nn++) {
            int s = nn * 16 + l15;
            bf16x4 p;
#pragma unroll
            for (int j = 0; j < 4; j++) {
                float v = acc[m][nn][j];
                p[j] = (__bf16)(v > 0.f ? v : 0.f);
            }
            int off = (s * 512 + f0 * 2) ^ ((s & 7) << 4);
            *(bf16x4*)(h1s + off) = p;
        }
    }
    __syncthreads();  // B5: h1 ready

    // ========== Layer 2: h2 = relu(h1 @ W2 + b2), K=256 ==========
    f32x4 acc2[4][4];
    {
        const int fb = wave * 64;
#pragma unroll
        for (int m = 0; m < 4; m++) {
            f32x4 bias = *(const f32x4*)(b2 + fb + m * 16 + l4 * 4);
#pragma unroll
            for (int nn = 0; nn < 4; nn++) acc2[m][nn] = bias;
        }
    }
    __builtin_amdgcn_s_setprio(1);
#pragma unroll
    for (int kk = 0; kk < 8; kk++) {
        bf16x8 bfr[4];
#pragma unroll
        for (int nn = 0; nn < 4; nn++) {
            int s = nn * 16 + l15;
            int off = (s * 512 + kk * 64 + l4 * 16) ^ ((s & 7) << 4);
            bfr[nn] = *(const bf16x8*)(h1s + off);
        }
        bf16x8 afr[4];
#pragma unroll
        for (int m = 0; m < 4; m++)
            afr[m] = *(const bf16x8*)(W2p + ((wave * 4 + m) * 8 + kk) * 512 + lane * 8);
#pragma unroll
        for (int m = 0; m < 4; m++)
#pragma unroll
            for (int nn = 0; nn < 4; nn++)
                acc2[m][nn] = __builtin_amdgcn_mfma_f32_16x16x32_bf16(
                    afr[m], bfr[nn], acc2[m][nn], 0, 0, 0);
    }
    __builtin_amdgcn_s_setprio(0);
    __syncthreads();  // B6: all h1 reads done; h2 may overwrite region
    // write h2 (relu, bf16)
#pragma unroll
    for (int m = 0; m < 4; m++) {
        int f0 = wave * 64 + m * 16 + l4 * 4;
#pragma unroll
        for (int nn = 0; nn < 4; nn++) {
            int s = nn * 16 + l15;
            bf16x4 p;
#pragma unroll
            for (int j = 0; j < 4; j++) {
                float v = acc2[m][nn][j];
                p[j] = (__bf16)(v > 0.f ? v : 0.f);
            }
            int off = (s * 512 + f0 * 2) ^ ((s & 7) << 4);
            *(bf16x4*)(h2s + off) = p;
        }
    }
    __syncthreads();  // B7: h2 ready

    // ========== Layer 3: enc = h2 @ W3 (bias in head), K=256 ==========
    f32x4 acc3[2][4];
#pragma unroll
    for (int m = 0; m < 2; m++)
#pragma unroll
        for (int nn = 0; nn < 4; nn++)
            acc3[m][nn] = (f32x4)(0.f);
    __builtin_amdgcn_s_setprio(1);
#pragma unroll
    for (int kk = 0; kk < 8; kk++) {
        bf16x8 bfr[4];
#pragma unroll
        for (int nn = 0; nn < 4; nn++) {
            int s = nn * 16 + l15;
            int off = (s * 512 + kk * 64 + l4 * 16) ^ ((s & 7) << 4);
            bfr[nn] = *(const bf16x8*)(h2s + off);
        }
        bf16x8 afr[2];
#pragma unroll
        for (int m = 0; m < 2; m++)
            afr[m] = *(const bf16x8*)(W3p + ((wave * 2 + m) * 8 + kk) * 512 + lane * 8);
#pragma unroll
        for (int m = 0; m < 2; m++)
#pragma unroll
            for (int nn = 0; nn < 4; nn++)
                acc3[m][nn] = __builtin_amdgcn_mfma_f32_16x16x32_bf16(
                    afr[m], bfr[nn], acc3[m][nn], 0, 0, 0);
    }
    __builtin_amdgcn_s_setprio(0);
    // reduce over samples, accumulate into bucket
    {
        float* bucket = part + (blockIdx.x & (NBUCKET - 1)) * 128;
#pragma unroll
        for (int m = 0; m < 2; m++) {
#pragma unroll
            for (int j = 0; j < 4; j++) {
                float v = 0.f;
#pragma unroll
                for (int nn = 0; nn < 4; nn++) {
                    int g = s0 + nn * 16 + l15;
                    float t = acc3[m][nn][j];
                    v += (g < n) ? t : 0.f;
                }
                for (int off = 1; off < 16; off <<= 1) v += __shfl_xor(v, off);
                if (l15 == 0) {
                    int f = wave * 32 + m * 16 + l4 * 4 + j;
                    atomicAdd(bucket + f, v);
                }
            }
        }
    }
}

// ---- head: agg = sum/n + b3; out = relu(agg@Wf1+bf1)@Wf2+bf2 (f32) ----
__global__ void head_kernel(const float* __restrict__ part, const float* __restrict__ b3,
                            const float* __restrict__ Wf1, const float* __restrict__ bf1,
                            const float* __restrict__ Wf2, const float* __restrict__ bf2,
                            float* __restrict__ out, int n)
{
    __shared__ float agg[128];
    __shared__ float t[256];
    const int tid = threadIdx.x;
    if (tid < 128) {
        float s = 0.f;
        for (int b = 0; b < NBUCKET; b++) s += part[b * 128 + tid];
        agg[tid] = s / (float)n + b3[tid];
    }
    __syncthreads();
    {
        float a = bf1[tid];
        for (int k = 0; k < 128; k++) a += agg[k] * Wf1[k * 256 + tid];
        t[tid] = a > 0.f ? a : 0.f;
    }
    __syncthreads();
    if (tid < 128) {
        float o = bf2[tid];
        for (int i = 0; i < 256; i++) o += t[i] * Wf2[i * 128 + tid];
        out[tid] = o;
    }
}

extern "C" void kernel_launch(void* const* d_in, const int* in_sizes, int n_in,
                              void* d_out, int out_size, void* d_ws, size_t ws_size,
                              hipStream_t stream) {
    const int*   triples = (const int*)d_in[0];
    const float* ent     = (const float*)d_in[1];
    const float* rel     = (const float*)d_in[2];
    const float* W1      = (const float*)d_in[3];
    const float* b1      = (const float*)d_in[4];
    const float* W2      = (const float*)d_in[5];
    const float* b2      = (const float*)d_in[6];
    const float* W3      = (const float*)d_in[7];
    const float* b3      = (const float*)d_in[8];
    const float* Wf1     = (const float*)d_in[9];
    const float* bf1     = (const float*)d_in[10];
    const float* Wf2     = (const float*)d_in[11];
    const float* bf2     = (const float*)d_in[12];
    float* out = (float*)d_out;
    const int n = in_sizes[0] / 3;

    // ws layout (bytes): W1p[0,196608) W2p[196608,327680) W3p[327680,393216)
    //                    part[393216,458752)
    __bf16* W1p = (__bf16*)d_ws;
    __bf16* W2p = (__bf16*)((char*)d_ws + 196608);
    __bf16* W3p = (__bf16*)((char*)d_ws + 327680);
    float*  prt = (float*)((char*)d_ws + 393216);

    prep_all<<<768, 256, 0, stream>>>(W1, W2, W3, W1p, W2p, W3p, prt);

    const int blocks = (n + BM - 1) / BM;
    mlp_main<<<blocks, 256, 0, stream>>>(triples, ent, rel, W1p, b1, W2p, b2, W3p, prt, n);
    head_kernel<<<1, 256, 0, stream>>>(prt, b3, Wf1, bf1, Wf2, bf2, out, n);
}

// Round 8
// 542.048 us; speedup vs baseline: 1.5904x; 1.4801x over previous
//
#include <hip/hip_runtime.h>
#include <hip/hip_bf16.h>

// StructuralEncoder: gather(3x128 f32) -> 384->256->256->128 MLP (relu,relu,linear)
// -> mean over 1M rows -> 128->256->128 head.
// R8: R7 structure (32KB LDS, split L1 K-loop, 7 barriers, late c2 gather) with
// __launch_bounds__(256,3): the (256,4) 128-VGPR cap forced spills (R6/R7:
// WRITE_SIZE 1.2-1.5 GB scratch). LDS=32KB still admits 5 blocks/CU; VGPR at
// ~100 admits more. Let the HW pack blocks; don't strangle the allocator.

#define EMBED 128
#define BM 64
#define NBUCKET 128

typedef __bf16 bf16x8 __attribute__((ext_vector_type(8)));
typedef __bf16 bf16x4 __attribute__((ext_vector_type(4)));
typedef float f32x4 __attribute__((ext_vector_type(4)));

// pack W (K x N row-major) into 16(feature)x32(k) A-frag tiles for 16x16x32,
// and zero partial buckets.
__global__ void prep_all(const float* __restrict__ W1, const float* __restrict__ W2,
                         const float* __restrict__ W3,
                         __bf16* __restrict__ W1p, __bf16* __restrict__ W2p,
                         __bf16* __restrict__ W3p, float* __restrict__ prt) {
    int idx = blockIdx.x * 256 + threadIdx.x;
    if (idx < NBUCKET * 128) prt[idx] = 0.f;
    const float* src; __bf16* dst; int K, N, e;
    if (idx < 98304)       { src = W1; dst = W1p; K = 384; N = 256; e = idx; }
    else if (idx < 163840) { src = W2; dst = W2p; K = 256; N = 256; e = idx - 98304; }
    else if (idx < 196608) { src = W3; dst = W3p; K = 256; N = 128; e = idx - 163840; }
    else return;
    int j = e & 7, l = (e >> 3) & 63, t = e >> 9;
    int KT = K >> 5;
    int kt = t % KT, mt = t / KT;
    int k  = kt * 32 + (l >> 4) * 8 + j;
    int nc = mt * 16 + (l & 15);
    dst[e] = (__bf16)src[k * N + nc];
}

// ---- main fused MLP over 64-row tiles ----
__global__ __launch_bounds__(256, 3) void mlp_main(
    const int* __restrict__ triples,
    const float* __restrict__ ent, const float* __restrict__ rel,
    const __bf16* __restrict__ W1p, const float* __restrict__ b1,
    const __bf16* __restrict__ W2p, const float* __restrict__ b2,
    const __bf16* __restrict__ W3p,
    float* __restrict__ part, int n)
{
    // LDS 32KB, time-multiplexed:
    //   xbuf0 [0,16K), xbuf1 [16K,32K): 64 rows x 256B (128 bf16) per c-chunk
    //   c0->xbuf0, c1->xbuf1; after kk0-7 reads, c2->xbuf0
    //   h1s/h2s overlay [0,32K) = 64 x 512B after all x reads done
    __shared__ unsigned char lds[32768];
    unsigned char* h1s = lds;
    unsigned char* h2s = lds;

    const int tid  = threadIdx.x;
    const int wave = tid >> 6;
    const int lane = tid & 63;
    const int l15  = lane & 15;
    const int l4   = lane >> 4;
    const int s0   = blockIdx.x * BM;
    const int sp   = tid >> 4;   // sample subgroup for staging
    const int ch   = tid & 15;   // 16B bf16 chunk (8 floats) within a c-row

    // ---- prologue: triple indices; issue c0+c1 gathers ----
    int rows[3][4];
#pragma unroll
    for (int p = 0; p < 4; p++) {
        int g = s0 + p * 16 + sp;
        const int* t = triples + (g < n ? g : 0) * 3;
        rows[0][p] = t[0]; rows[1][p] = t[1]; rows[2][p] = t[2];
    }
    {
        float4 ga[2][4], gb[2][4];
#pragma unroll
        for (int c = 0; c < 2; c++) {
            const float* tbl = (c == 1) ? rel : ent;
#pragma unroll
            for (int p = 0; p < 4; p++) {
                const float* src = tbl + (long)rows[c][p] * EMBED + ch * 8;
                ga[c][p] = *(const float4*)src;
                gb[c][p] = *(const float4*)(src + 4);
            }
        }
        // cvt + write c0 -> xbuf0, c1 -> xbuf1 (256B row stride, swizzled)
#pragma unroll
        for (int c = 0; c < 2; c++)
#pragma unroll
            for (int p = 0; p < 4; p++) {
                bf16x8 w;
                w[0] = (__bf16)ga[c][p].x; w[1] = (__bf16)ga[c][p].y;
                w[2] = (__bf16)ga[c][p].z; w[3] = (__bf16)ga[c][p].w;
                w[4] = (__bf16)gb[c][p].x; w[5] = (__bf16)gb[c][p].y;
                w[6] = (__bf16)gb[c][p].z; w[7] = (__bf16)gb[c][p].w;
                int s = p * 16 + sp;
                int off = c * 16384 + ((s * 256 + ch * 16) ^ ((s & 7) << 4));
                *(bf16x8*)(lds + off) = w;
            }
    }
    __syncthreads();  // B1: c0,c1 ready

    // ========== Layer 1: h1 = relu(x @ W1 + b1), K=384, 12 k-steps ==========
    f32x4 acc[4][4];
    {
        const int fb = wave * 64;
#pragma unroll
        for (int m = 0; m < 4; m++) {
            f32x4 bias = *(const f32x4*)(b1 + fb + m * 16 + l4 * 4);
#pragma unroll
            for (int nn = 0; nn < 4; nn++) acc[m][nn] = bias;
        }
    }
    __builtin_amdgcn_s_setprio(1);
#pragma unroll
    for (int kk = 0; kk < 8; kk++) {
        bf16x8 bfr[4];
#pragma unroll
        for (int nn = 0; nn < 4; nn++) {
            int s = nn * 16 + l15;
            int off = (kk >> 2) * 16384 +
                      ((s * 256 + (kk & 3) * 64 + l4 * 16) ^ ((s & 7) << 4));
            bfr[nn] = *(const bf16x8*)(lds + off);
        }
        bf16x8 afr[4];
#pragma unroll
        for (int m = 0; m < 4; m++)
            afr[m] = *(const bf16x8*)(W1p + ((wave * 4 + m) * 12 + kk) * 512 + lane * 8);
#pragma unroll
        for (int m = 0; m < 4; m++)
#pragma unroll
            for (int nn = 0; nn < 4; nn++)
                acc[m][nn] = __builtin_amdgcn_mfma_f32_16x16x32_bf16(
                    afr[m], bfr[nn], acc[m][nn], 0, 0, 0);
    }
    __builtin_amdgcn_s_setprio(0);
    // issue c2 gathers (live range spans only B2)
    float4 g2a[4], g2b[4];
#pragma unroll
    for (int p = 0; p < 4; p++) {
        const float* src = ent + (long)rows[2][p] * EMBED + ch * 8;
        g2a[p] = *(const float4*)src;
        g2b[p] = *(const float4*)(src + 4);
    }
    __syncthreads();  // B2: kk0-7 reads done; xbuf0 may be overwritten
    // write c2 -> xbuf0
#pragma unroll
    for (int p = 0; p < 4; p++) {
        bf16x8 w;
        w[0] = (__bf16)g2a[p].x; w[1] = (__bf16)g2a[p].y;
        w[2] = (__bf16)g2a[p].z; w[3] = (__bf16)g2a[p].w;
        w[4] = (__bf16)g2b[p].x; w[5] = (__bf16)g2b[p].y;
        w[6] = (__bf16)g2b[p].z; w[7] = (__bf16)g2b[p].w;
        int s = p * 16 + sp;
        int off = (s * 256 + ch * 16) ^ ((s & 7) << 4);
        *(bf16x8*)(lds + off) = w;
    }
    __syncthreads();  // B3: c2 ready
    __builtin_amdgcn_s_setprio(1);
#pragma unroll
    for (int kk = 8; kk < 12; kk++) {
        bf16x8 bfr[4];
#pragma unroll
        for (int nn = 0; nn < 4; nn++) {
            int s = nn * 16 + l15;
            int off = (s * 256 + (kk & 3) * 64 + l4 * 16) ^ ((s & 7) << 4);
            bfr[nn] = *(const bf16x8*)(lds + off);
        }
        bf16x8 afr[4];
#pragma unroll
        for (int m = 0; m < 4; m++)
            afr[m] = *(const bf16x8*)(W1p + ((wave * 4 + m) * 12 + kk) * 512 + lane * 8);
#pragma unroll
        for (int m = 0; m < 4; m++)
#pragma unroll
            for (int nn = 0; nn < 4; nn++)
                acc[m][nn] = __builtin_amdgcn_mfma_f32_16x16x32_bf16(
                    afr[m], bfr[nn], acc[m][nn], 0, 0, 0);
    }
    __builtin_amdgcn_s_setprio(0);
    __syncthreads();  // B4: all x reads done; h1 may overlay [0,32K)
    // write h1 (relu, bf16)
#pragma unroll
    for (int m = 0; m < 4; m++) {
        int f0 = wave * 64 + m * 16 + l4 * 4;
#pragma unroll
        for (int nn = 0; nn < 4; nn++) {
            int s = nn * 16 + l15;
            bf16x4 p;
#pragma unroll
            for (int j = 0; j < 4; j++) {
                float v = acc[m][nn][j];
                p[j] = (__bf16)(v > 0.f ? v : 0.f);
            }
            int off = (s * 512 + f0 * 2) ^ ((s & 7) << 4);
            *(bf16x4*)(h1s + off) = p;
        }
    }
    __syncthreads();  // B5: h1 ready

    // ========== Layer 2: h2 = relu(h1 @ W2 + b2), K=256 ==========
    f32x4 acc2[4][4];
    {
        const int fb = wave * 64;
#pragma unroll
        for (int m = 0; m < 4; m++) {
            f32x4 bias = *(const f32x4*)(b2 + fb + m * 16 + l4 * 4);
#pragma unroll
            for (int nn = 0; nn < 4; nn++) acc2[m][nn] = bias;
        }
    }
    __builtin_amdgcn_s_setprio(1);
#pragma unroll
    for (int kk = 0; kk < 8; kk++) {
        bf16x8 bfr[4];
#pragma unroll
        for (int nn = 0; nn < 4; nn++) {
            int s = nn * 16 + l15;
            int off = (s * 512 + kk * 64 + l4 * 16) ^ ((s & 7) << 4);
            bfr[nn] = *(const bf16x8*)(h1s + off);
        }
        bf16x8 afr[4];
#pragma unroll
        for (int m = 0; m < 4; m++)
            afr[m] = *(const bf16x8*)(W2p + ((wave * 4 + m) * 8 + kk) * 512 + lane * 8);
#pragma unroll
        for (int m = 0; m < 4; m++)
#pragma unroll
            for (int nn = 0; nn < 4; nn++)
                acc2[m][nn] = __builtin_amdgcn_mfma_f32_16x16x32_bf16(
                    afr[m], bfr[nn], acc2[m][nn], 0, 0, 0);
    }
    __builtin_amdgcn_s_setprio(0);
    __syncthreads();  // B6: all h1 reads done; h2 may overwrite region
    // write h2 (relu, bf16)
#pragma unroll
    for (int m = 0; m < 4; m++) {
        int f0 = wave * 64 + m * 16 + l4 * 4;
#pragma unroll
        for (int nn = 0; nn < 4; nn++) {
            int s = nn * 16 + l15;
            bf16x4 p;
#pragma unroll
            for (int j = 0; j < 4; j++) {
                float v = acc2[m][nn][j];
                p[j] = (__bf16)(v > 0.f ? v : 0.f);
            }
            int off = (s * 512 + f0 * 2) ^ ((s & 7) << 4);
            *(bf16x4*)(h2s + off) = p;
        }
    }
    __syncthreads();  // B7: h2 ready

    // ========== Layer 3: enc = h2 @ W3 (bias in head), K=256 ==========
    f32x4 acc3[2][4];
#pragma unroll
    for (int m = 0; m < 2; m++)
#pragma unroll
        for (int nn = 0; nn < 4; nn++)
            acc3[m][nn] = (f32x4)(0.f);
    __builtin_amdgcn_s_setprio(1);
#pragma unroll
    for (int kk = 0; kk < 8; kk++) {
        bf16x8 bfr[4];
#pragma unroll
        for (int nn = 0; nn < 4; nn++) {
            int s = nn * 16 + l15;
            int off = (s * 512 + kk * 64 + l4 * 16) ^ ((s & 7) << 4);
            bfr[nn] = *(const bf16x8*)(h2s + off);
        }
        bf16x8 afr[2];
#pragma unroll
        for (int m = 0; m < 2; m++)
            afr[m] = *(const bf16x8*)(W3p + ((wave * 2 + m) * 8 + kk) * 512 + lane * 8);
#pragma unroll
        for (int m = 0; m < 2; m++)
#pragma unroll
            for (int nn = 0; nn < 4; nn++)
                acc3[m][nn] = __builtin_amdgcn_mfma_f32_16x16x32_bf16(
                    afr[m], bfr[nn], acc3[m][nn], 0, 0, 0);
    }
    __builtin_amdgcn_s_setprio(0);
    // reduce over samples, accumulate into bucket
    {
        float* bucket = part + (blockIdx.x & (NBUCKET - 1)) * 128;
#pragma unroll
        for (int m = 0; m < 2; m++) {
#pragma unroll
            for (int j = 0; j < 4; j++) {
                float v = 0.f;
#pragma unroll
                for (int nn = 0; nn < 4; nn++) {
                    int g = s0 + nn * 16 + l15;
                    float t = acc3[m][nn][j];
                    v += (g < n) ? t : 0.f;
                }
                for (int off = 1; off < 16; off <<= 1) v += __shfl_xor(v, off);
                if (l15 == 0) {
                    int f = wave * 32 + m * 16 + l4 * 4 + j;
                    atomicAdd(bucket + f, v);
                }
            }
        }
    }
}

// ---- head: agg = sum/n + b3; out = relu(agg@Wf1+bf1)@Wf2+bf2 (f32) ----
__global__ void head_kernel(const float* __restrict__ part, const float* __restrict__ b3,
                            const float* __restrict__ Wf1, const float* __restrict__ bf1,
                            const float* __restrict__ Wf2, const float* __restrict__ bf2,
                            float* __restrict__ out, int n)
{
    __shared__ float agg[128];
    __shared__ float t[256];
    const int tid = threadIdx.x;
    if (tid < 128) {
        float s = 0.f;
        for (int b = 0; b < NBUCKET; b++) s += part[b * 128 + tid];
        agg[tid] = s / (float)n + b3[tid];
    }
    __syncthreads();
    {
        float a = bf1[tid];
        for (int k = 0; k < 128; k++) a += agg[k] * Wf1[k * 256 + tid];
        t[tid] = a > 0.f ? a : 0.f;
    }
    __syncthreads();
    if (tid < 128) {
        float o = bf2[tid];
        for (int i = 0; i < 256; i++) o += t[i] * Wf2[i * 128 + tid];
        out[tid] = o;
    }
}

extern "C" void kernel_launch(void* const* d_in, const int* in_sizes, int n_in,
                              void* d_out, int out_size, void* d_ws, size_t ws_size,
                              hipStream_t stream) {
    const int*   triples = (const int*)d_in[0];
    const float* ent     = (const float*)d_in[1];
    const float* rel     = (const float*)d_in[2];
    const float* W1      = (const float*)d_in[3];
    const float* b1      = (const float*)d_in[4];
    const float* W2      = (const float*)d_in[5];
    const float* b2      = (const float*)d_in[6];
    const float* W3      = (const float*)d_in[7];
    const float* b3      = (const float*)d_in[8];
    const float* Wf1     = (const float*)d_in[9];
    const float* bf1     = (const float*)d_in[10];
    const float* Wf2     = (const float*)d_in[11];
    const float* bf2     = (const float*)d_in[12];
    float* out = (float*)d_out;
    const int n = in_sizes[0] / 3;

    // ws layout (bytes): W1p[0,196608) W2p[196608,327680) W3p[327680,393216)
    //                    part[393216,458752)
    __bf16* W1p = (__bf16*)d_ws;
    __bf16* W2p = (__bf16*)((char*)d_ws + 196608);
    __bf16* W3p = (__bf16*)((char*)d_ws + 327680);
    float*  prt = (float*)((char*)d_ws + 393216);

    prep_all<<<768, 256, 0, stream>>>(W1, W2, W3, W1p, W2p, W3p, prt);

    const int blocks = (n + BM - 1) / BM;
    mlp_main<<<blocks, 256, 0, stream>>>(triples, ent, rel, W1p, b1, W2p, b2, W3p, prt, n);
    head_kernel<<<1, 256, 0, stream>>>(prt, b3, Wf1, bf1, Wf2, bf2, out, n);
}